// Round 9
// baseline (55.229 us; speedup 1.0000x reference)
//
#include <hip/hip_runtime.h>
#include <math.h>

#define Bb 4
#define Nn 4096
#define Hh 128
#define Ff 64
#define CAP 128  // max neighbors kept per row (deg ~41 +/- 6.4; 13 sigma)

typedef __attribute__((ext_vector_type(8))) short bf16x8;
typedef __attribute__((ext_vector_type(4))) float f32x4;

// bf16 helpers (RNE)
__device__ __forceinline__ unsigned short f2bf(float f) {
  unsigned int u = __float_as_uint(f);
  u += 0x7fffu + ((u >> 16) & 1u);
  return (unsigned short)(u >> 16);
}
__device__ __forceinline__ float bf2f(unsigned short h) {
  return __uint_as_float(((unsigned int)h) << 16);
}

// ---------------------------------------------------------------------------
// qkv_kernel: 256 blocks x 64 rows, bf16 MFMA (same math as R8's QKV half,
// which passed correctness). x staged bf16 in swizzled LDS (byte-XOR
// (row&7)<<4 kills the 16-way conflict on stride-256B ds_read_b128, G4);
// W lives in registers as 12 B-fragments/wave loaded once from L2-hot global.
// mfma_f32_16x16x32_bf16: A row=lane&15, k=8*(lane>>4)+j; B col=lane&15;
// D col=lane&15, row=4*(lane>>4)+reg (m89-verified; R8 refcheck passed).
// Wave w owns n-strip [48w,48w+48) of [q(0:64)|k(64:128)|v(128:192)].
// Standalone (was fused with CSR in R8): fusion forced the CSR half to carry
// this kernel's VGPR/LDS footprint; split is also the measurability fix.
// ---------------------------------------------------------------------------
__global__ __launch_bounds__(256) void qkv_kernel(
    const float* __restrict__ x,
    const float* __restrict__ Wq,
    const float* __restrict__ Wk,
    const float* __restrict__ Wv,
    float* __restrict__ q,
    unsigned short* __restrict__ kb,
    unsigned short* __restrict__ vb) {
  __shared__ short xs[64 * 128];  // bf16, swizzled

  const int tid = threadIdx.x;
  const int w = tid >> 6;
  const int lane = tid & 63;

  const int row0 = (int)blockIdx.x * 64;
  const int half = lane >> 4;  // 0..3
  const int l16 = lane & 15;

  // stage x: 64 rows x 128 f32 -> packed bf16, swizzled LDS
  const float4* xg = (const float4*)(x + (size_t)row0 * Hh);
#pragma unroll
  for (int j = 0; j < 8; ++j) {
    const int idx = tid + 256 * j;  // float4 index; 32 per row
    const int row = idx >> 5;
    const int c4 = idx & 31;
    const float4 xv = xg[idx];
    uint2 p;
    p.x = (unsigned)f2bf(xv.x) | ((unsigned)f2bf(xv.y) << 16);
    p.y = (unsigned)f2bf(xv.z) | ((unsigned)f2bf(xv.w) << 16);
    const int addr = (row * 256 + c4 * 8) ^ ((row & 7) << 4);
    *(uint2*)((char*)xs + addr) = p;
  }

  // B-fragments: wave w covers global n in [48w, 48w+48) = 3 n-tiles
  bf16x8 bfr[3][4];
#pragma unroll
  for (int nt = 0; nt < 3; ++nt) {
    const int n0g = w * 48 + nt * 16;
    const float* Wm = (n0g < 64) ? Wq : (n0g < 128) ? Wk : Wv;
    const int c0 = n0g & 63;
#pragma unroll
    for (int ks = 0; ks < 4; ++ks) {
      bf16x8 f;
#pragma unroll
      for (int j = 0; j < 8; ++j) {
        const int kr = ks * 32 + half * 8 + j;
        f[j] = (short)f2bf(Wm[kr * Ff + c0 + l16]);
      }
      bfr[nt][ks] = f;
    }
  }
  __syncthreads();

  f32x4 acc[4][3];
#pragma unroll
  for (int mt = 0; mt < 4; ++mt)
#pragma unroll
    for (int nt = 0; nt < 3; ++nt)
#pragma unroll
      for (int r = 0; r < 4; ++r) acc[mt][nt][r] = 0.f;

#pragma unroll
  for (int mt = 0; mt < 4; ++mt) {
    const int arow = mt * 16 + l16;
    const int abase = arow * 256;
    const int aswz = (arow & 7) << 4;
#pragma unroll
    for (int ks = 0; ks < 4; ++ks) {
      const int addr = (abase + ks * 64 + half * 16) ^ aswz;
      const bf16x8 a = *(const bf16x8*)((const char*)xs + addr);
#pragma unroll
      for (int nt = 0; nt < 3; ++nt) {
        acc[mt][nt] = __builtin_amdgcn_mfma_f32_16x16x32_bf16(
            a, bfr[nt][ks], acc[mt][nt], 0, 0, 0);
      }
    }
  }

  // epilogue: D col=lane&15, row=4*half+reg
#pragma unroll
  for (int mt = 0; mt < 4; ++mt) {
#pragma unroll
    for (int nt = 0; nt < 3; ++nt) {
      const int n0g = w * 48 + nt * 16;
      const int col = (n0g & 63) + l16;
#pragma unroll
      for (int r = 0; r < 4; ++r) {
        const size_t rowg = (size_t)row0 + mt * 16 + half * 4 + r;
        const float val = acc[mt][nt][r];
        if (n0g < 64)
          q[rowg * Ff + col] = val;
        else if (n0g < 128)
          kb[rowg * Ff + col] = f2bf(val);
        else
          vb[rowg * Ff + col] = f2bf(val);
      }
    }
  }
}

// ---------------------------------------------------------------------------
// csr_kernel: adj -> CSR. 1024 blocks x 4 waves, ONE row per wave (4x the
// TLP of R8's fused half, and no longer carrying the QKV VGPR/LDS footprint).
// 16 hoisted float4 loads stream the row; ballot compaction scatters u16
// positions into LDS; ONE coalesced 256B store per row replaces R8's 64
// divergent global stores.
// ---------------------------------------------------------------------------
__global__ __launch_bounds__(256) void csr_kernel(
    const float* __restrict__ adj,
    unsigned short* __restrict__ g_nbr,
    int* __restrict__ g_cnt) {
  __shared__ __align__(8) unsigned short stg[4][CAP];

  const int tid = threadIdx.x;
  const int w = tid >> 6;
  const int lane = tid & 63;

  const int n = (int)blockIdx.x * 4 + w;
  const float* arow = adj + (size_t)n * Nn;

  // zero-init this wave's staging row so g_nbr stays deterministic
  ((ushort2*)stg[w])[lane] = make_ushort2(0, 0);

  float4 a4[16];  // hoist all loads: deep MLP, full-rate stream
#pragma unroll
  for (int c = 0; c < 16; ++c) a4[c] = ((const float4*)arow)[c * 64 + lane];

  const unsigned long long ltmask =
      (lane == 0) ? 0ull : (~0ull >> (64 - lane));
  int off = 0;
#pragma unroll
  for (int c = 0; c < 16; ++c) {
#pragma unroll
    for (int comp = 0; comp < 4; ++comp) {
      const float val = comp == 0 ? a4[c].x
                      : comp == 1 ? a4[c].y
                      : comp == 2 ? a4[c].z
                                  : a4[c].w;
      const bool nz = (val != 0.f);
      const unsigned long long mm = __ballot(nz);
      if (nz) {
        const int pos = off + (int)__popcll(mm & ltmask);
        if (pos < CAP)
          stg[w][pos] = (unsigned short)(c * 256 + 4 * lane + comp);
      }
      off += (int)__popcll(mm);
    }
  }

  if (lane == 0) g_cnt[n] = off < CAP ? off : CAP;
  // same-wave LDS write->read; compiler inserts lgkmcnt
  ((ushort2*)(g_nbr + (size_t)n * CAP))[lane] = ((const ushort2*)stg[w])[lane];
}

// ---------------------------------------------------------------------------
// attn_kernel: sparse masked attention over CSR, bf16 k/v. (unchanged)
// One block (4 waves) per row n; wave w = batch b.
// Score: 4-lane-group k gather, line-minimal (row = 128 B = 2 lines).
//   Group shfl(1,2) completes the dot; all 4 lanes hold identical s -> tile
//   psum reduce spans GROUPS ONLY (offsets 32..4; 2,1 would 4x-count: R3 bug).
// PV: lane = feature, p broadcast from LDS.
// out = acc/L + sum_v (reference adds adj back: +1 per neighbor).
// ---------------------------------------------------------------------------
__global__ __launch_bounds__(256) void attn_kernel(
    const unsigned short* __restrict__ g_nbr,
    const int* __restrict__ g_cnt,
    const float* __restrict__ q,
    const unsigned short* __restrict__ kb,
    const unsigned short* __restrict__ vb,
    float* __restrict__ out) {
  __shared__ __align__(8) unsigned short nbr[CAP];
  __shared__ float qs[4][64];
  __shared__ float ps[4][64];

  const int n = blockIdx.x;
  const int tid = threadIdx.x;
  const int w = tid >> 6;
  const int lane = tid & 63;

  qs[w][lane] = q[((size_t)w * Nn + n) * Ff + lane];
  if (w == 0) {
    ((ushort2*)nbr)[lane] = ((const ushort2*)(g_nbr + (size_t)n * CAP))[lane];
  }
  const int tot = g_cnt[n];
  __syncthreads();

  const int b = w;
  const unsigned short* kbb = kb + (size_t)b * Nn * Ff;
  const unsigned short* vbb = vb + (size_t)b * Nn * Ff;

  const int g = lane >> 2;  // row group 0..15
  const int sl = lane & 3;  // sub-lane

  float4 q0a = *(const float4*)&qs[b][8 * sl];
  float4 q0b = *(const float4*)&qs[b][8 * sl + 4];
  float4 q1a = *(const float4*)&qs[b][32 + 8 * sl];
  float4 q1b = *(const float4*)&qs[b][32 + 8 * sl + 4];

  float M = -INFINITY, L = 0.f, acc = 0.f, vsum = 0.f;

  const int ntiles = (tot + 63) >> 6;
  for (int t = 0; t < ntiles; ++t) {
    const int tbase = t << 6;

    float s0, s1, s2, s3;
#define BPAIR(u, qlo, qhi, a)                                   \
    {                                                           \
      const float flo = __uint_as_float((u) << 16);             \
      const float fhi = __uint_as_float((u) & 0xffff0000u);     \
      a = fmaf(qlo, flo, a);                                    \
      a = fmaf(qhi, fhi, a);                                    \
    }
#define DOT_ROW(i, sdst)                                                  \
    {                                                                     \
      const int idx = tbase + g + 16 * (i);                               \
      const bool valid = idx < tot;                                       \
      const int m = valid ? (int)nbr[idx] : 0;                            \
      const char* krow = (const char*)(kbb + (size_t)m * Ff);             \
      const uint4 k0 = *(const uint4*)(krow + 16 * sl);                   \
      const uint4 k1 = *(const uint4*)(krow + 64 + 16 * sl);              \
      float a = 0.f;                                                      \
      BPAIR(k0.x, q0a.x, q0a.y, a)                                        \
      BPAIR(k0.y, q0a.z, q0a.w, a)                                        \
      BPAIR(k0.z, q0b.x, q0b.y, a)                                        \
      BPAIR(k0.w, q0b.z, q0b.w, a)                                        \
      BPAIR(k1.x, q1a.x, q1a.y, a)                                        \
      BPAIR(k1.y, q1a.z, q1a.w, a)                                        \
      BPAIR(k1.z, q1b.x, q1b.y, a)                                        \
      BPAIR(k1.w, q1b.z, q1b.w, a)                                        \
      a += __shfl_xor(a, 1, 64);                                          \
      a += __shfl_xor(a, 2, 64);                                          \
      sdst = valid ? a * 0.125f : -INFINITY;                              \
    }
    DOT_ROW(0, s0)
    DOT_ROW(1, s1)
    DOT_ROW(2, s2)
    DOT_ROW(3, s3)
#undef DOT_ROW
#undef BPAIR

    float lm = fmaxf(fmaxf(s0, s1), fmaxf(s2, s3));
#pragma unroll
    for (int o = 32; o; o >>= 1) lm = fmaxf(lm, __shfl_xor(lm, o, 64));
    const float newM = fmaxf(M, lm);

    const float p0 = (s0 == -INFINITY) ? 0.f : __expf(s0 - newM);
    const float p1 = (s1 == -INFINITY) ? 0.f : __expf(s1 - newM);
    const float p2 = (s2 == -INFINITY) ? 0.f : __expf(s2 - newM);
    const float p3 = (s3 == -INFINITY) ? 0.f : __expf(s3 - newM);

    float psum = ((p0 + p1) + (p2 + p3));
#pragma unroll
    for (int o = 32; o >= 4; o >>= 1) psum += __shfl_xor(psum, o, 64);

    const float corr = __expf(M - newM);  // t==0: exp(-inf)=0, L=acc=0
    L = L * corr + psum;
    acc *= corr;
    M = newM;

    const float pw = sl == 0 ? p0 : sl == 1 ? p1 : sl == 2 ? p2 : p3;
    ps[w][g + 16 * sl] = pw;

    const int jmax = min(64, tot - tbase);
#pragma unroll 4
    for (int j = 0; j < jmax; ++j) {
      const int m = nbr[tbase + j];                       // LDS broadcast
      const float vf = bf2f(vbb[(size_t)m * Ff + lane]);  // coalesced 128B
      acc = fmaf(ps[w][j], vf, acc);                      // p broadcast
      vsum += vf;
    }
  }

  out[((size_t)b * Nn + n) * Ff + lane] = acc / L + vsum;
}

// ---------------------------------------------------------------------------
extern "C" void kernel_launch(void* const* d_in, const int* in_sizes, int n_in,
                              void* d_out, int out_size, void* d_ws, size_t ws_size,
                              hipStream_t stream) {
  const float* x = (const float*)d_in[0];
  const float* Wq = (const float*)d_in[1];
  const float* Wk = (const float*)d_in[2];
  const float* Wv = (const float*)d_in[3];
  const float* adj = (const float*)d_in[4];
  float* out = (float*)d_out;

  char* ws = (char*)d_ws;
  const size_t rows = (size_t)Bb * Nn;  // 16384
  float* q = (float*)ws;                                       // 4 MiB
  unsigned short* kb = (unsigned short*)(ws + rows * Ff * 4);  // 2 MiB
  unsigned short* vb = (unsigned short*)(ws + rows * Ff * 4 + rows * Ff * 2);
  unsigned short* g_nbr = (unsigned short*)(ws + rows * Ff * 8);  // 1 MiB
  int* g_cnt = (int*)(ws + rows * Ff * 8 + (size_t)Nn * CAP * 2);

  qkv_kernel<<<dim3(256), dim3(256), 0, stream>>>(x, Wq, Wk, Wv, q, kb, vb);
  csr_kernel<<<dim3(Nn / 4), dim3(256), 0, stream>>>(adj, g_nbr, g_cnt);
  attn_kernel<<<dim3(Nn), dim3(256), 0, stream>>>(g_nbr, g_cnt, q, kb, vb, out);
}

// Round 10
// 50.064 us; speedup vs baseline: 1.1032x; 1.1032x over previous
//
#include <hip/hip_runtime.h>
#include <math.h>

#define Bb 4
#define Nn 4096
#define Hh 128
#define Ff 64
#define NBR_CAP 192  // deg ~41 +/- 6.4; 128 sufficed for 9 rounds, 192 = margin

typedef __attribute__((ext_vector_type(8))) short bf16x8;
typedef __attribute__((ext_vector_type(4))) float f32x4;

// bf16 helpers (RNE)
__device__ __forceinline__ unsigned short f2bf(float f) {
  unsigned int u = __float_as_uint(f);
  u += 0x7fffu + ((u >> 16) & 1u);
  return (unsigned short)(u >> 16);
}
__device__ __forceinline__ float bf2f(unsigned short h) {
  return __uint_as_float(((unsigned int)h) << 16);
}

// ---------------------------------------------------------------------------
// qkv_kernel: 256 blocks x 64 rows, bf16 MFMA (unchanged from R8/R9 —
// refcheck-passed). x staged bf16 in swizzled LDS (byte-XOR (row&7)<<4 kills
// the 16-way conflict on stride-256B ds_read_b128, G4); W in registers as 12
// B-fragments/wave loaded once from L2-hot global.
// mfma_f32_16x16x32_bf16: A row=lane&15, k=8*(lane>>4)+j; B col=lane&15;
// D col=lane&15, row=4*(lane>>4)+reg. Wave w owns n-strip [48w,48w+48) of
// [q(0:64)|k(64:128)|v(128:192)].
// ---------------------------------------------------------------------------
__global__ __launch_bounds__(256) void qkv_kernel(
    const float* __restrict__ x,
    const float* __restrict__ Wq,
    const float* __restrict__ Wk,
    const float* __restrict__ Wv,
    float* __restrict__ q,
    unsigned short* __restrict__ kb,
    unsigned short* __restrict__ vb) {
  __shared__ short xs[64 * 128];  // bf16, swizzled

  const int tid = threadIdx.x;
  const int w = tid >> 6;
  const int lane = tid & 63;

  const int row0 = (int)blockIdx.x * 64;
  const int half = lane >> 4;  // 0..3
  const int l16 = lane & 15;

  const float4* xg = (const float4*)(x + (size_t)row0 * Hh);
#pragma unroll
  for (int j = 0; j < 8; ++j) {
    const int idx = tid + 256 * j;  // float4 index; 32 per row
    const int row = idx >> 5;
    const int c4 = idx & 31;
    const float4 xv = xg[idx];
    uint2 p;
    p.x = (unsigned)f2bf(xv.x) | ((unsigned)f2bf(xv.y) << 16);
    p.y = (unsigned)f2bf(xv.z) | ((unsigned)f2bf(xv.w) << 16);
    const int addr = (row * 256 + c4 * 8) ^ ((row & 7) << 4);
    *(uint2*)((char*)xs + addr) = p;
  }

  bf16x8 bfr[3][4];
#pragma unroll
  for (int nt = 0; nt < 3; ++nt) {
    const int n0g = w * 48 + nt * 16;
    const float* Wm = (n0g < 64) ? Wq : (n0g < 128) ? Wk : Wv;
    const int c0 = n0g & 63;
#pragma unroll
    for (int ks = 0; ks < 4; ++ks) {
      bf16x8 f;
#pragma unroll
      for (int j = 0; j < 8; ++j) {
        const int kr = ks * 32 + half * 8 + j;
        f[j] = (short)f2bf(Wm[kr * Ff + c0 + l16]);
      }
      bfr[nt][ks] = f;
    }
  }
  __syncthreads();

  f32x4 acc[4][3];
#pragma unroll
  for (int mt = 0; mt < 4; ++mt)
#pragma unroll
    for (int nt = 0; nt < 3; ++nt)
#pragma unroll
      for (int r = 0; r < 4; ++r) acc[mt][nt][r] = 0.f;

#pragma unroll
  for (int mt = 0; mt < 4; ++mt) {
    const int arow = mt * 16 + l16;
    const int abase = arow * 256;
    const int aswz = (arow & 7) << 4;
#pragma unroll
    for (int ks = 0; ks < 4; ++ks) {
      const int addr = (abase + ks * 64 + half * 16) ^ aswz;
      const bf16x8 a = *(const bf16x8*)((const char*)xs + addr);
#pragma unroll
      for (int nt = 0; nt < 3; ++nt) {
        acc[mt][nt] = __builtin_amdgcn_mfma_f32_16x16x32_bf16(
            a, bfr[nt][ks], acc[mt][nt], 0, 0, 0);
      }
    }
  }

#pragma unroll
  for (int mt = 0; mt < 4; ++mt) {
#pragma unroll
    for (int nt = 0; nt < 3; ++nt) {
      const int n0g = w * 48 + nt * 16;
      const int col = (n0g & 63) + l16;
#pragma unroll
      for (int r = 0; r < 4; ++r) {
        const size_t rowg = (size_t)row0 + mt * 16 + half * 4 + r;
        const float val = acc[mt][nt][r];
        if (n0g < 64)
          q[rowg * Ff + col] = val;
        else if (n0g < 128)
          kb[rowg * Ff + col] = f2bf(val);
        else
          vb[rowg * Ff + col] = f2bf(val);
      }
    }
  }
}

// ---------------------------------------------------------------------------
// attn_kernel: FUSED adj scan + sparse masked attention, bf16 k/v.
// One block (4 waves) per row n; wave w = batch b.
//
// Scan (replaces the standalone CSR kernel -- R9 showed de-fusion costs 8us;
// this reads each adj row exactly once, inside the block that needs it, so
// HBM streaming of some blocks overlaps the L2 gather of others):
//   UNORDERED compaction -- neighbor order only perturbs fp rounding (~1e-6
//   vs 0.94 margin). Per-thread count of its 16 entries -> wave shfl_up
//   scan -> cross-wave LDS prefix -> each thread writes its own entries.
//   Kills R4's 64-serial-ballot dependency chain (now ~16 parallel VALU
//   iters + one 6-step scan). Deterministic (fixed thread->entry mapping).
//
// Score: 4-lane-group k gather, line-minimal (bf16 row = 128 B = 2 lines).
//   Group shfl(1,2) completes the dot; all 4 lanes hold identical s -> tile
//   psum reduce spans GROUPS ONLY (offsets 32..4; 2,1 would 4x-count: R3 bug).
// PV: lane = feature, p broadcast from LDS.
// out = acc/L + sum_v (reference adds adj back: +1 per neighbor).
// ---------------------------------------------------------------------------
__global__ __launch_bounds__(256) void attn_kernel(
    const float* __restrict__ adj,
    const float* __restrict__ q,
    const unsigned short* __restrict__ kb,
    const unsigned short* __restrict__ vb,
    float* __restrict__ out) {
  __shared__ __align__(8) unsigned short nbr[NBR_CAP];
  __shared__ float qs[4][64];
  __shared__ float ps[4][64];
  __shared__ int wcnt[4];

  const int n = blockIdx.x;
  const int tid = threadIdx.x;
  const int w = tid >> 6;
  const int lane = tid & 63;

  // stage q early (overlaps the adj stream)
  qs[w][lane] = q[((size_t)w * Nn + n) * Ff + lane];

  // ---- scan phase ----
  const float* arow = adj + (size_t)n * Nn;
  float4 a4[4];
#pragma unroll
  for (int j = 0; j < 4; ++j) a4[j] = ((const float4*)arow)[tid + 256 * j];

  int cnt = 0;
#pragma unroll
  for (int j = 0; j < 4; ++j) {
    cnt += (a4[j].x != 0.f) + (a4[j].y != 0.f) + (a4[j].z != 0.f) +
           (a4[j].w != 0.f);
  }

  // wave inclusive scan
  int inc = cnt;
#pragma unroll
  for (int o = 1; o < 64; o <<= 1) {
    const int t = __shfl_up(inc, o, 64);
    if (lane >= o) inc += t;
  }
  if (lane == 63) wcnt[w] = inc;
  __syncthreads();

  int base = 0, tot = 0;
#pragma unroll
  for (int w2 = 0; w2 < 4; ++w2) {
    const int c = wcnt[w2];
    if (w2 < w) base += c;
    tot += c;
  }
  if (tot > NBR_CAP) tot = NBR_CAP;

  int pos = base + (inc - cnt);  // this thread's exclusive offset
#pragma unroll
  for (int j = 0; j < 4; ++j) {
    const int col0 = 4 * (tid + 256 * j);
#pragma unroll
    for (int comp = 0; comp < 4; ++comp) {
      const float val = comp == 0 ? a4[j].x
                      : comp == 1 ? a4[j].y
                      : comp == 2 ? a4[j].z
                                  : a4[j].w;
      if (val != 0.f) {
        if (pos < NBR_CAP) nbr[pos] = (unsigned short)(col0 + comp);
        ++pos;
      }
    }
  }
  __syncthreads();

  // ---- attention ----
  const int b = w;
  const unsigned short* kbb = kb + (size_t)b * Nn * Ff;
  const unsigned short* vbb = vb + (size_t)b * Nn * Ff;

  const int g = lane >> 2;  // row group 0..15
  const int sl = lane & 3;  // sub-lane

  float4 q0a = *(const float4*)&qs[b][8 * sl];
  float4 q0b = *(const float4*)&qs[b][8 * sl + 4];
  float4 q1a = *(const float4*)&qs[b][32 + 8 * sl];
  float4 q1b = *(const float4*)&qs[b][32 + 8 * sl + 4];

  float M = -INFINITY, L = 0.f, acc = 0.f, vsum = 0.f;

  const int ntiles = (tot + 63) >> 6;
  for (int t = 0; t < ntiles; ++t) {
    const int tbase = t << 6;

    float s0, s1, s2, s3;
#define BPAIR(u, qlo, qhi, a)                                   \
    {                                                           \
      const float flo = __uint_as_float((u) << 16);             \
      const float fhi = __uint_as_float((u) & 0xffff0000u);     \
      a = fmaf(qlo, flo, a);                                    \
      a = fmaf(qhi, fhi, a);                                    \
    }
#define DOT_ROW(i, sdst)                                                  \
    {                                                                     \
      const int idx = tbase + g + 16 * (i);                               \
      const bool valid = idx < tot;                                       \
      const int m = valid ? (int)nbr[idx] : 0;                            \
      const char* krow = (const char*)(kbb + (size_t)m * Ff);             \
      const uint4 k0 = *(const uint4*)(krow + 16 * sl);                   \
      const uint4 k1 = *(const uint4*)(krow + 64 + 16 * sl);              \
      float a = 0.f;                                                      \
      BPAIR(k0.x, q0a.x, q0a.y, a)                                        \
      BPAIR(k0.y, q0a.z, q0a.w, a)                                        \
      BPAIR(k0.z, q0b.x, q0b.y, a)                                        \
      BPAIR(k0.w, q0b.z, q0b.w, a)                                        \
      BPAIR(k1.x, q1a.x, q1a.y, a)                                        \
      BPAIR(k1.y, q1a.z, q1a.w, a)                                        \
      BPAIR(k1.z, q1b.x, q1b.y, a)                                        \
      BPAIR(k1.w, q1b.z, q1b.w, a)                                        \
      a += __shfl_xor(a, 1, 64);                                          \
      a += __shfl_xor(a, 2, 64);                                          \
      sdst = valid ? a * 0.125f : -INFINITY;                              \
    }
    DOT_ROW(0, s0)
    DOT_ROW(1, s1)
    DOT_ROW(2, s2)
    DOT_ROW(3, s3)
#undef DOT_ROW
#undef BPAIR

    float lm = fmaxf(fmaxf(s0, s1), fmaxf(s2, s3));
#pragma unroll
    for (int o = 32; o; o >>= 1) lm = fmaxf(lm, __shfl_xor(lm, o, 64));
    const float newM = fmaxf(M, lm);

    const float p0 = (s0 == -INFINITY) ? 0.f : __expf(s0 - newM);
    const float p1 = (s1 == -INFINITY) ? 0.f : __expf(s1 - newM);
    const float p2 = (s2 == -INFINITY) ? 0.f : __expf(s2 - newM);
    const float p3 = (s3 == -INFINITY) ? 0.f : __expf(s3 - newM);

    float psum = ((p0 + p1) + (p2 + p3));
#pragma unroll
    for (int o = 32; o >= 4; o >>= 1) psum += __shfl_xor(psum, o, 64);

    const float corr = __expf(M - newM);  // t==0: exp(-inf)=0, L=acc=0
    L = L * corr + psum;
    acc *= corr;
    M = newM;

    const float pw = sl == 0 ? p0 : sl == 1 ? p1 : sl == 2 ? p2 : p3;
    ps[w][g + 16 * sl] = pw;

    const int jmax = min(64, tot - tbase);
#pragma unroll 4
    for (int j = 0; j < jmax; ++j) {
      const int m = nbr[tbase + j];                       // LDS broadcast
      const float vf = bf2f(vbb[(size_t)m * Ff + lane]);  // coalesced 128B
      acc = fmaf(ps[w][j], vf, acc);                      // p broadcast
      vsum += vf;
    }
  }

  out[((size_t)b * Nn + n) * Ff + lane] = acc / L + vsum;
}

// ---------------------------------------------------------------------------
extern "C" void kernel_launch(void* const* d_in, const int* in_sizes, int n_in,
                              void* d_out, int out_size, void* d_ws, size_t ws_size,
                              hipStream_t stream) {
  const float* x = (const float*)d_in[0];
  const float* Wq = (const float*)d_in[1];
  const float* Wk = (const float*)d_in[2];
  const float* Wv = (const float*)d_in[3];
  const float* adj = (const float*)d_in[4];
  float* out = (float*)d_out;

  char* ws = (char*)d_ws;
  const size_t rows = (size_t)Bb * Nn;  // 16384
  float* q = (float*)ws;                                       // 4 MiB
  unsigned short* kb = (unsigned short*)(ws + rows * Ff * 4);  // 2 MiB
  unsigned short* vb = (unsigned short*)(ws + rows * Ff * 4 + rows * Ff * 2);

  qkv_kernel<<<dim3(256), dim3(256), 0, stream>>>(x, Wq, Wk, Wv, q, kb, vb);
  attn_kernel<<<dim3(Nn), dim3(256), 0, stream>>>(adj, q, kb, vb, out);
}